// Round 3
// baseline (104.384 us; speedup 1.0000x reference)
//
#include <hip/hip_runtime.h>
#include <hip/hip_bf16.h>

#define ALPHA 0.25f
#define DELTA 0.5f
#define GRID  2048
#define BLOCK 256

// ---------------------------------------------------------------------------
// Fused: elementwise loss + block partials + last-block final reduction.
// The workspace counter is reset to 0 by hipMemsetAsync before every launch,
// so "winner" == the block observing old == GRID-1 (strictly the last one).
// Release: __threadfence() before atomicAdd. Acquire: device-scope atomic
// loads of partials in the winner block.
// ---------------------------------------------------------------------------
__global__ void __launch_bounds__(BLOCK)
dafl_fused_kernel(const float* __restrict__ y_pred,
                  const float* __restrict__ y_true,
                  float* __restrict__ partials,
                  unsigned int* __restrict__ counter,
                  float* __restrict__ out,
                  int n4,            // number of float4 elements
                  float inv_n)
{
    const float4* __restrict__ p4 = reinterpret_cast<const float4*>(y_pred);
    const float4* __restrict__ t4 = reinterpret_cast<const float4*>(y_true);

    const int idx    = blockIdx.x * BLOCK + threadIdx.x;
    const int stride = GRID * BLOCK;
    const int iters  = n4 / stride;          // exact-trip main loop (16 for 2^23)

    float acc = 0.0f;
    int i = idx;

    #pragma unroll 4
    for (int it = 0; it < iters; ++it, i += stride) {
        float4 p = p4[i];
        float4 t = t4[i];
        #pragma unroll
        for (int j = 0; j < 4; ++j) {
            float pp = (&p.x)[j];
            float tt = (&t.x)[j];

            float r = rintf(tt);                         // round-half-to-even
            r = fminf(fmaxf(r, 0.0f), 3.0f);             // clamp to [0,3]
            int cls = (int)r;
            float w = (cls == 0) ? 1.0f
                    : (cls == 1) ? 4.0f
                    : (cls == 2) ? 3.0f
                    :              2.0f;

            float d = fabsf(pp - tt);
            float f = fminf(d * 2.0f, 1.0f);             // clip(d/0.5,0,1)
            f = f * f;                                   // ^GAMMA(=2)
            float base = (d < DELTA) ? (d * d) : (d - 0.25f);  // huber, beta=0.5

            acc += ALPHA * f * base * w;
        }
    }
    for (; i < n4; i += stride) {                        // tail (empty here)
        float4 p = p4[i];
        float4 t = t4[i];
        #pragma unroll
        for (int j = 0; j < 4; ++j) {
            float pp = (&p.x)[j], tt = (&t.x)[j];
            float r = rintf(tt);
            r = fminf(fmaxf(r, 0.0f), 3.0f);
            int cls = (int)r;
            float w = (cls == 0) ? 1.0f : (cls == 1) ? 4.0f : (cls == 2) ? 3.0f : 2.0f;
            float d = fabsf(pp - tt);
            float f = fminf(d * 2.0f, 1.0f); f = f * f;
            float base = (d < DELTA) ? (d * d) : (d - 0.25f);
            acc += ALPHA * f * base * w;
        }
    }

    // ---- wave (64) then block (4 waves) reduction ----
    #pragma unroll
    for (int off = 32; off > 0; off >>= 1)
        acc += __shfl_down(acc, off, 64);

    __shared__ float smem[4];
    __shared__ int   s_done;
    const int lane = threadIdx.x & 63;
    const int wave = threadIdx.x >> 6;
    if (lane == 0) smem[wave] = acc;
    __syncthreads();

    if (threadIdx.x == 0) {
        float s = smem[0] + smem[1] + smem[2] + smem[3];
        __hip_atomic_store(&partials[blockIdx.x], s,
                           __ATOMIC_RELAXED, __HIP_MEMORY_SCOPE_AGENT);
        __threadfence();                               // release
        unsigned int old = atomicAdd(counter, 1u);     // device-scope
        s_done = (old == (GRID - 1u));                 // strictly last block
    }
    __syncthreads();

    if (s_done) {
        float a2 = 0.0f;
        for (int j = threadIdx.x; j < GRID; j += BLOCK)
            a2 += __hip_atomic_load(&partials[j],
                                    __ATOMIC_ACQUIRE, __HIP_MEMORY_SCOPE_AGENT);

        #pragma unroll
        for (int off = 32; off > 0; off >>= 1)
            a2 += __shfl_down(a2, off, 64);

        __syncthreads();                 // smem reuse barrier
        if (lane == 0) smem[wave] = a2;
        __syncthreads();
        if (threadIdx.x == 0)
            out[0] = (smem[0] + smem[1] + smem[2] + smem[3]) * inv_n;
    }
}

extern "C" void kernel_launch(void* const* d_in, const int* in_sizes, int n_in,
                              void* d_out, int out_size, void* d_ws, size_t ws_size,
                              hipStream_t stream) {
    const float* y_pred = (const float*)d_in[0];
    const float* y_true = (const float*)d_in[1];
    float* out = (float*)d_out;

    float* partials        = (float*)d_ws;                     // GRID floats
    unsigned int* counter  = (unsigned int*)((char*)d_ws + GRID * sizeof(float));

    long long n = (long long)in_sizes[0];   // B*N = 2^25
    int n4 = (int)(n >> 2);

    // reset the arrival counter every call (async memset is capture-legal)
    hipMemsetAsync(counter, 0, sizeof(unsigned int), stream);

    dafl_fused_kernel<<<GRID, BLOCK, 0, stream>>>(
        y_pred, y_true, partials, counter, out, n4, (float)(1.0 / (double)n));
}

// Round 4
// 53.241 us; speedup vs baseline: 1.9606x; 1.9606x over previous
//
#include <hip/hip_runtime.h>
#include <hip/hip_bf16.h>

#define ALPHA 0.25f
#define DELTA 0.5f
#define GRID  2048
#define BLOCK 256

__device__ __forceinline__ float dafl_elem(float pp, float tt) {
    float r = rintf(tt);                          // round-half-to-even (jnp.round)
    r = fminf(fmaxf(r, 0.0f), 3.0f);              // clamp [0,3]
    int cls = (int)r;
    float w = (cls == 0) ? 1.0f
            : (cls == 1) ? 4.0f
            : (cls == 2) ? 3.0f
            :              2.0f;

    float d = fabsf(pp - tt);
    float f = fminf(d * 2.0f, 1.0f);              // clip(d/0.5, 0, 1)
    f = f * f;                                    // ^GAMMA(=2)
    float base = (d < DELTA) ? (d * d) : (d - 0.25f);   // huber, beta=0.5
    return ALPHA * f * base * w;
}

__device__ __forceinline__ float dafl_quad(float4 p, float4 t) {
    float s = 0.0f;
    #pragma unroll
    for (int j = 0; j < 4; ++j)
        s += dafl_elem((&p.x)[j], (&t.x)[j]);
    return s;
}

// ---------------------------------------------------------------------------
// Kernel 1: grid-stride elementwise loss, 2-deep software pipeline (prefetch
// next float4 pair before computing current), block partial -> d_ws.
// ---------------------------------------------------------------------------
__global__ void __launch_bounds__(BLOCK)
dafl_partial_kernel(const float* __restrict__ y_pred,
                    const float* __restrict__ y_true,
                    float* __restrict__ partials,
                    int n4)   // number of float4 elements
{
    const float4* __restrict__ p4 = reinterpret_cast<const float4*>(y_pred);
    const float4* __restrict__ t4 = reinterpret_cast<const float4*>(y_true);

    const int idx    = blockIdx.x * BLOCK + threadIdx.x;
    const int stride = GRID * BLOCK;

    float acc = 0.0f;

    int i = idx;
    if (i < n4) {
        float4 p = p4[i];
        float4 t = t4[i];
        for (int inext = i + stride; inext < n4; inext += stride) {
            float4 pn = p4[inext];        // issue next pair BEFORE computing
            float4 tn = t4[inext];        // current -> 2 pairs in flight
            acc += dafl_quad(p, t);
            p = pn; t = tn;
        }
        acc += dafl_quad(p, t);           // drain
    }

    // wave-level reduction (64 lanes)
    #pragma unroll
    for (int off = 32; off > 0; off >>= 1)
        acc += __shfl_down(acc, off, 64);

    __shared__ float smem[4];
    const int lane = threadIdx.x & 63;
    const int wave = threadIdx.x >> 6;
    if (lane == 0) smem[wave] = acc;
    __syncthreads();

    if (threadIdx.x == 0)
        partials[blockIdx.x] = smem[0] + smem[1] + smem[2] + smem[3];
}

// ---------------------------------------------------------------------------
// Kernel 2: reduce per-block partials, write the mean. One block.
// ---------------------------------------------------------------------------
__global__ void __launch_bounds__(256)
dafl_final_kernel(const float* __restrict__ partials,
                  float* __restrict__ out,
                  int num_partials,
                  float inv_n)
{
    float acc = 0.0f;
    for (int i = threadIdx.x; i < num_partials; i += 256)
        acc += partials[i];

    #pragma unroll
    for (int off = 32; off > 0; off >>= 1)
        acc += __shfl_down(acc, off, 64);

    __shared__ float smem[4];
    int lane = threadIdx.x & 63;
    int wave = threadIdx.x >> 6;
    if (lane == 0) smem[wave] = acc;
    __syncthreads();

    if (threadIdx.x == 0)
        out[0] = (smem[0] + smem[1] + smem[2] + smem[3]) * inv_n;
}

extern "C" void kernel_launch(void* const* d_in, const int* in_sizes, int n_in,
                              void* d_out, int out_size, void* d_ws, size_t ws_size,
                              hipStream_t stream) {
    const float* y_pred = (const float*)d_in[0];
    const float* y_true = (const float*)d_in[1];
    float* out = (float*)d_out;
    float* partials = (float*)d_ws;

    long long n = (long long)in_sizes[0];   // B*N = 2^25
    int n4 = (int)(n >> 2);

    dafl_partial_kernel<<<GRID, BLOCK, 0, stream>>>(y_pred, y_true, partials, n4);
    dafl_final_kernel<<<1, 256, 0, stream>>>(partials, out, GRID,
                                             (float)(1.0 / (double)n));
}